// Round 1
// baseline (856.345 us; speedup 1.0000x reference)
//
#include <hip/hip_runtime.h>

// Problem constants (fixed by reference)
#define DIMC 256   // feature/channel dim (c == e == d)
#define BSZ  32
#define MDIM 2048
#define NDIM 2048

// ---------------------------------------------------------------------------
// phi kernel: phi[b,e,m] = relu(alpha * sum_c W[c,e] * X[b,c,m])
// Tile: 64(e) x 64(m), block 16x16 threads, 4x4 outputs/thread, K chunks of 16.
// W is [256,256] row-major (c rows, e cols -> e contiguous).
// X is [B,256,Mdim] (m contiguous).
// ---------------------------------------------------------------------------
__global__ __launch_bounds__(256) void phi_kernel(
    const float* __restrict__ X, const float* __restrict__ W,
    float* __restrict__ phi, float alpha, int Mdim) {
  const int b  = blockIdx.z;
  const int m0 = blockIdx.x * 64;
  const int e0 = blockIdx.y * 64;
  __shared__ float sW[16][64 + 1];  // [k][e]
  __shared__ float sX[16][64 + 1];  // [k][m]
  const float* Xb = X + (size_t)b * DIMC * Mdim;
  const int tx = threadIdx.x;           // m
  const int ty = threadIdx.y;           // e
  const int tid = ty * 16 + tx;
  const int lr = tid >> 4;              // 0..15  (k row for loads)
  const int lc = (tid & 15) << 2;       // 0,4,...,60 (col*4 for loads)
  float acc[4][4] = {};
  for (int k0 = 0; k0 < DIMC; k0 += 16) {
    float4 w4 = *(const float4*)(W  + (size_t)(k0 + lr) * DIMC + e0 + lc);
    float4 x4 = *(const float4*)(Xb + (size_t)(k0 + lr) * Mdim + m0 + lc);
    sW[lr][lc + 0] = w4.x; sW[lr][lc + 1] = w4.y;
    sW[lr][lc + 2] = w4.z; sW[lr][lc + 3] = w4.w;
    sX[lr][lc + 0] = x4.x; sX[lr][lc + 1] = x4.y;
    sX[lr][lc + 2] = x4.z; sX[lr][lc + 3] = x4.w;
    __syncthreads();
#pragma unroll
    for (int kc = 0; kc < 16; ++kc) {
      float a[4], bv[4];
#pragma unroll
      for (int i = 0; i < 4; ++i) a[i]  = sW[kc][ty * 4 + i];
#pragma unroll
      for (int j = 0; j < 4; ++j) bv[j] = sX[kc][tx * 4 + j];
#pragma unroll
      for (int i = 0; i < 4; ++i)
#pragma unroll
        for (int j = 0; j < 4; ++j) acc[i][j] += a[i] * bv[j];
    }
    __syncthreads();
  }
  float* pb = phi + (size_t)b * DIMC * Mdim;
#pragma unroll
  for (int i = 0; i < 4; ++i) {
    const int e = e0 + ty * 4 + i;
#pragma unroll
    for (int j = 0; j < 4; ++j) {
      const int m = m0 + tx * 4 + j;
      float v = acc[i][j] * alpha;
      pb[(size_t)e * Mdim + m] = v > 0.f ? v : 0.f;
    }
  }
}

// ---------------------------------------------------------------------------
// rowsum[b*256+e] = sum_n phi_k[b,e,n]   (one 256-thread block per row)
// ---------------------------------------------------------------------------
__global__ __launch_bounds__(256) void rowsum_kernel(
    const float* __restrict__ phi_k, float* __restrict__ rowsum) {
  const int row = blockIdx.x;  // b*256 + e
  const float* p = phi_k + (size_t)row * NDIM;
  float s = 0.f;
  for (int i = threadIdx.x; i < NDIM; i += 256) s += p[i];
  __shared__ float red[256];
  red[threadIdx.x] = s;
  __syncthreads();
  for (int w = 128; w >= 1; w >>= 1) {
    if (threadIdx.x < w) red[threadIdx.x] += red[threadIdx.x + w];
    __syncthreads();
  }
  if (threadIdx.x == 0) rowsum[row] = red[0];
}

// ---------------------------------------------------------------------------
// kv[b,e,d] = sum_n phi_k[b,e,n] * value[b,d,n]
// Tile: 64(e) x 64(d), K = 2048 in chunks of 16.
// Both operands are row-major with n contiguous -> load 64x16 sub-tiles and
// store transposed into LDS as [k][row].
// ---------------------------------------------------------------------------
__global__ __launch_bounds__(256) void kv_kernel(
    const float* __restrict__ phi_k, const float* __restrict__ value,
    float* __restrict__ kv) {
  const int b  = blockIdx.z;
  const int d0 = blockIdx.x * 64;
  const int e0 = blockIdx.y * 64;
  __shared__ float sA[16][64 + 1];  // [k][e]
  __shared__ float sB[16][64 + 1];  // [k][d]
  const float* Ab = phi_k + (size_t)b * DIMC * NDIM;
  const float* Bb = value + (size_t)b * DIMC * NDIM;
  const int tx = threadIdx.x;       // d
  const int ty = threadIdx.y;       // e
  const int tid = ty * 16 + tx;
  const int lrow = tid >> 2;        // 0..63  (e or d row for loads)
  const int lc4  = (tid & 3) << 2;  // 0,4,8,12 (n within chunk)
  float acc[4][4] = {};
  for (int n0 = 0; n0 < NDIM; n0 += 16) {
    float4 a4 = *(const float4*)(Ab + (size_t)(e0 + lrow) * NDIM + n0 + lc4);
    float4 b4 = *(const float4*)(Bb + (size_t)(d0 + lrow) * NDIM + n0 + lc4);
    sA[lc4 + 0][lrow] = a4.x; sA[lc4 + 1][lrow] = a4.y;
    sA[lc4 + 2][lrow] = a4.z; sA[lc4 + 3][lrow] = a4.w;
    sB[lc4 + 0][lrow] = b4.x; sB[lc4 + 1][lrow] = b4.y;
    sB[lc4 + 2][lrow] = b4.z; sB[lc4 + 3][lrow] = b4.w;
    __syncthreads();
#pragma unroll
    for (int kc = 0; kc < 16; ++kc) {
      float a[4], bv[4];
#pragma unroll
      for (int i = 0; i < 4; ++i) a[i]  = sA[kc][ty * 4 + i];
#pragma unroll
      for (int j = 0; j < 4; ++j) bv[j] = sB[kc][tx * 4 + j];
#pragma unroll
      for (int i = 0; i < 4; ++i)
#pragma unroll
        for (int j = 0; j < 4; ++j) acc[i][j] += a[i] * bv[j];
    }
    __syncthreads();
  }
  float* kvb = kv + (size_t)b * DIMC * DIMC;
#pragma unroll
  for (int i = 0; i < 4; ++i) {
    const int e = e0 + ty * 4 + i;
#pragma unroll
    for (int j = 0; j < 4; ++j) {
      const int d = d0 + tx * 4 + j;
      kvb[(size_t)e * DIMC + d] = acc[i][j];
    }
  }
}

// ---------------------------------------------------------------------------
// scale[b,m] = 1 / (sum_e phi_q[b,e,m] * rowsum[b,e] + 1e-8)
// ---------------------------------------------------------------------------
__global__ __launch_bounds__(256) void scale_kernel(
    const float* __restrict__ phi_q, const float* __restrict__ rowsum,
    float* __restrict__ scale) {
  const int b = blockIdx.y;
  const int m = blockIdx.x * 256 + threadIdx.x;
  const float* pq = phi_q + (size_t)b * DIMC * MDIM + m;
  const float* rs = rowsum + b * DIMC;
  float s = 0.f;
  for (int e = 0; e < DIMC; ++e) s += pq[(size_t)e * MDIM] * rs[e];
  scale[b * MDIM + m] = 1.f / (s + 1e-8f);
}

// ---------------------------------------------------------------------------
// out[b,d,m] = scale[b,m] * sum_e kv[b,e,d] * phi_q[b,e,m]
// Same structure as phi_kernel: kv plays W ([e][d], d contiguous),
// phi_q plays X ([e][m], m contiguous). Column scale applied at epilogue.
// ---------------------------------------------------------------------------
__global__ __launch_bounds__(256) void out_kernel(
    const float* __restrict__ kv, const float* __restrict__ phi_q,
    const float* __restrict__ scale, float* __restrict__ out) {
  const int b  = blockIdx.z;
  const int m0 = blockIdx.x * 64;
  const int d0 = blockIdx.y * 64;
  __shared__ float sA[16][64 + 1];  // [k=e][d]
  __shared__ float sX[16][64 + 1];  // [k=e][m]
  const float* kvb = kv    + (size_t)b * DIMC * DIMC;
  const float* pqb = phi_q + (size_t)b * DIMC * MDIM;
  const int tx = threadIdx.x;        // m
  const int ty = threadIdx.y;        // d
  const int tid = ty * 16 + tx;
  const int lr = tid >> 4;
  const int lc = (tid & 15) << 2;
  float acc[4][4] = {};
  for (int k0 = 0; k0 < DIMC; k0 += 16) {
    float4 a4 = *(const float4*)(kvb + (size_t)(k0 + lr) * DIMC + d0 + lc);
    float4 x4 = *(const float4*)(pqb + (size_t)(k0 + lr) * MDIM + m0 + lc);
    sA[lr][lc + 0] = a4.x; sA[lr][lc + 1] = a4.y;
    sA[lr][lc + 2] = a4.z; sA[lr][lc + 3] = a4.w;
    sX[lr][lc + 0] = x4.x; sX[lr][lc + 1] = x4.y;
    sX[lr][lc + 2] = x4.z; sX[lr][lc + 3] = x4.w;
    __syncthreads();
#pragma unroll
    for (int kc = 0; kc < 16; ++kc) {
      float a[4], bv[4];
#pragma unroll
      for (int i = 0; i < 4; ++i) a[i]  = sA[kc][ty * 4 + i];
#pragma unroll
      for (int j = 0; j < 4; ++j) bv[j] = sX[kc][tx * 4 + j];
#pragma unroll
      for (int i = 0; i < 4; ++i)
#pragma unroll
        for (int j = 0; j < 4; ++j) acc[i][j] += a[i] * bv[j];
    }
    __syncthreads();
  }
  float* ob = out + (size_t)b * DIMC * MDIM;
  const float* sc = scale + b * MDIM;
#pragma unroll
  for (int j = 0; j < 4; ++j) {
    const int m = m0 + tx * 4 + j;
    const float s = sc[m];
#pragma unroll
    for (int i = 0; i < 4; ++i) {
      const int d = d0 + ty * 4 + i;
      ob[(size_t)d * MDIM + m] = acc[i][j] * s;
    }
  }
}

extern "C" void kernel_launch(void* const* d_in, const int* in_sizes, int n_in,
                              void* d_out, int out_size, void* d_ws, size_t ws_size,
                              hipStream_t stream) {
  const float* query = (const float*)d_in[0];  // [B,256,M]
  const float* key   = (const float*)d_in[1];  // [B,256,N]
  const float* value = (const float*)d_in[2];  // [B,256,N]
  const float* W     = (const float*)d_in[3];  // [256,256]
  float* out = (float*)d_out;                  // [B,256,M]

  // Workspace layout (floats): ~137 MB total
  float* ws     = (float*)d_ws;
  float* phi_q  = ws;                                    // B*256*M = 16.8M
  float* phi_k  = phi_q  + (size_t)BSZ * DIMC * MDIM;    // B*256*N
  float* kv     = phi_k  + (size_t)BSZ * DIMC * NDIM;    // B*256*256
  float* rowsum = kv     + (size_t)BSZ * DIMC * DIMC;    // B*256
  float* scale  = rowsum + (size_t)BSZ * DIMC;           // B*M

  const dim3 blk(16, 16);
  const dim3 gphi(MDIM / 64, DIMC / 64, BSZ);

  // 1) phi_q = relu(W^T @ query) / 16    (alpha commutes with relu, alpha>0)
  hipLaunchKernelGGL(phi_kernel, gphi, blk, 0, stream, query, W, phi_q,
                     1.0f / 16.0f, MDIM);
  // 2) phi_k = relu(W^T @ key)
  hipLaunchKernelGGL(phi_kernel, gphi, blk, 0, stream, key, W, phi_k, 1.0f,
                     NDIM);
  // 3) rowsum over n
  hipLaunchKernelGGL(rowsum_kernel, dim3(BSZ * DIMC), dim3(256), 0, stream,
                     phi_k, rowsum);
  // 4) kv = phi_k @ value^T
  hipLaunchKernelGGL(kv_kernel, dim3(DIMC / 64, DIMC / 64, BSZ), blk, 0,
                     stream, phi_k, value, kv);
  // 5) scale = 1/(phi_q^T rowsum + 1e-8)
  hipLaunchKernelGGL(scale_kernel, dim3(MDIM / 256, BSZ), dim3(256), 0, stream,
                     phi_q, rowsum, scale);
  // 6) out = kv^T @ (phi_q * scale)
  hipLaunchKernelGGL(out_kernel, gphi, blk, 0, stream, kv, phi_q, scale, out);
}

// Round 2
// 324.738 us; speedup vs baseline: 2.6370x; 2.6370x over previous
//
#include <hip/hip_runtime.h>

// Problem constants
#define DIMC 256
#define BSZ  32
#define MDIM 2048
#define NDIM 2048

typedef __attribute__((ext_vector_type(8))) short bf16x8;   // 8 bf16 (4 VGPRs)
typedef __attribute__((ext_vector_type(4))) float f32x4;    // MFMA acc

static __device__ __forceinline__ unsigned short f2bf(float x) {
  unsigned int u = __float_as_uint(x);
  u += 0x7fffu + ((u >> 16) & 1u);          // round-to-nearest-even
  return (unsigned short)(u >> 16);
}
static __device__ __forceinline__ float bf2f(unsigned short h) {
  return __uint_as_float(((unsigned int)h) << 16);
}

// ---------------------------------------------------------------------------
// Wt[e][c] = bf16(W[c][e])  (tiny one-shot transpose+convert)
// ---------------------------------------------------------------------------
__global__ __launch_bounds__(256) void wt_kernel(
    const float* __restrict__ W, unsigned short* __restrict__ Wt) {
  const int e = blockIdx.x, c = threadIdx.x;
  Wt[e * 256 + c] = f2bf(W[c * 256 + e]);
}

// ---------------------------------------------------------------------------
// phi_k[b][e][n] = relu(sum_c Wt[e][c] * key[b][c][n])   bf16 out, n-contig
// 128(e) x 128(n) tile, K=256, BK=32. A=Wt natural; B=key transpose-staged.
// ---------------------------------------------------------------------------
__global__ __launch_bounds__(256) void phik_kernel(
    const float* __restrict__ key, const unsigned short* __restrict__ Wt,
    unsigned short* __restrict__ phi_k) {
  __shared__ unsigned short As[128 * 40];  // [e][c], stride 40 bf16 = 80 B
  __shared__ unsigned short Bs[128 * 40];  // [n][c]
  const int b = blockIdx.z;
  const int n0 = blockIdx.x * 128;
  const int e0 = blockIdx.y * 128;
  const int t = threadIdx.x;
  const int lane = t & 63, wave = t >> 6;
  const int wr = wave >> 1, wc = wave & 1;
  const int q = lane >> 4, l15 = lane & 15;
  const float* keyb = key + (size_t)b * DIMC * NDIM;
  f32x4 acc[4][4];
#pragma unroll
  for (int i = 0; i < 4; ++i)
#pragma unroll
    for (int j = 0; j < 4; ++j) acc[i][j] = (f32x4){0.f, 0.f, 0.f, 0.f};

  const int arow = t >> 2, ac8 = (t & 3) << 3;       // A staging coords
  const int nidx = t & 127, ch = (t >> 7) << 4;      // B staging coords

  for (int k0 = 0; k0 < DIMC; k0 += 32) {
    __syncthreads();
    // stage A: Wt rows e0..e0+127, cols k0..k0+31 (natural bf16, 16B loads)
    {
      uint4 v0 = *(const uint4*)(Wt + (size_t)(e0 + arow) * 256 + k0 + ac8);
      uint4 v1 = *(const uint4*)(Wt + (size_t)(e0 + arow + 64) * 256 + k0 + ac8);
      *(uint4*)&As[arow * 40 + ac8] = v0;
      *(uint4*)&As[(arow + 64) * 40 + ac8] = v1;
    }
    // stage B: key[c][n] -> Bs[n][c], convert fp32->bf16
    {
      const float* src = keyb + (size_t)(k0 + ch) * NDIM + n0 + nidx;
      unsigned short tmp[16] __attribute__((aligned(16)));
#pragma unroll
      for (int i = 0; i < 16; ++i) tmp[i] = f2bf(src[(size_t)i * NDIM]);
      *(uint4*)&Bs[nidx * 40 + ch] = *(const uint4*)&tmp[0];
      *(uint4*)&Bs[nidx * 40 + ch + 8] = *(const uint4*)&tmp[8];
    }
    __syncthreads();
    bf16x8 a[4], bv[4];
#pragma unroll
    for (int i = 0; i < 4; ++i)
      a[i] = *(const bf16x8*)&As[(wr * 64 + i * 16 + l15) * 40 + q * 8];
#pragma unroll
    for (int j = 0; j < 4; ++j)
      bv[j] = *(const bf16x8*)&Bs[(wc * 64 + j * 16 + l15) * 40 + q * 8];
#pragma unroll
    for (int i = 0; i < 4; ++i)
#pragma unroll
      for (int j = 0; j < 4; ++j)
        acc[i][j] =
            __builtin_amdgcn_mfma_f32_16x16x32_bf16(a[i], bv[j], acc[i][j], 0, 0, 0);
  }
  unsigned short* dst = phi_k + (size_t)b * DIMC * NDIM;
#pragma unroll
  for (int i = 0; i < 4; ++i)
#pragma unroll
    for (int j = 0; j < 4; ++j) {
      const int n = n0 + wc * 64 + j * 16 + l15;
#pragma unroll
      for (int r = 0; r < 4; ++r) {
        const int e = e0 + wr * 64 + i * 16 + q * 4 + r;
        float v = acc[i][j][r];
        dst[(size_t)e * NDIM + n] = f2bf(v > 0.f ? v : 0.f);
      }
    }
}

// ---------------------------------------------------------------------------
// phi_q[b][m][e] = relu(sum_c query[b][c][m] * Wt[e][c]) / 16   bf16, e-contig
// 128(m) x 128(e) tile. A=query transpose-staged; B=Wt natural.
// ---------------------------------------------------------------------------
__global__ __launch_bounds__(256) void phiq_kernel(
    const float* __restrict__ query, const unsigned short* __restrict__ Wt,
    unsigned short* __restrict__ phi_q) {
  __shared__ unsigned short As[128 * 40];  // [m][c]
  __shared__ unsigned short Bs[128 * 40];  // [e][c]
  const int b = blockIdx.z;
  const int m0 = blockIdx.x * 128;
  const int e0 = blockIdx.y * 128;
  const int t = threadIdx.x;
  const int lane = t & 63, wave = t >> 6;
  const int wr = wave >> 1, wc = wave & 1;
  const int q = lane >> 4, l15 = lane & 15;
  const float* qb = query + (size_t)b * DIMC * MDIM;
  f32x4 acc[4][4];
#pragma unroll
  for (int i = 0; i < 4; ++i)
#pragma unroll
    for (int j = 0; j < 4; ++j) acc[i][j] = (f32x4){0.f, 0.f, 0.f, 0.f};

  const int brow = t >> 2, bc8 = (t & 3) << 3;
  const int midx = t & 127, ch = (t >> 7) << 4;

  for (int k0 = 0; k0 < DIMC; k0 += 32) {
    __syncthreads();
    // stage A: query[c][m] -> As[m][c]
    {
      const float* src = qb + (size_t)(k0 + ch) * MDIM + m0 + midx;
      unsigned short tmp[16] __attribute__((aligned(16)));
#pragma unroll
      for (int i = 0; i < 16; ++i) tmp[i] = f2bf(src[(size_t)i * MDIM]);
      *(uint4*)&As[midx * 40 + ch] = *(const uint4*)&tmp[0];
      *(uint4*)&As[midx * 40 + ch + 8] = *(const uint4*)&tmp[8];
    }
    // stage B: Wt rows e0..e0+127
    {
      uint4 v0 = *(const uint4*)(Wt + (size_t)(e0 + brow) * 256 + k0 + bc8);
      uint4 v1 = *(const uint4*)(Wt + (size_t)(e0 + brow + 64) * 256 + k0 + bc8);
      *(uint4*)&Bs[brow * 40 + bc8] = v0;
      *(uint4*)&Bs[(brow + 64) * 40 + bc8] = v1;
    }
    __syncthreads();
    bf16x8 a[4], bv[4];
#pragma unroll
    for (int i = 0; i < 4; ++i)
      a[i] = *(const bf16x8*)&As[(wr * 64 + i * 16 + l15) * 40 + q * 8];
#pragma unroll
    for (int j = 0; j < 4; ++j)
      bv[j] = *(const bf16x8*)&Bs[(wc * 64 + j * 16 + l15) * 40 + q * 8];
#pragma unroll
    for (int i = 0; i < 4; ++i)
#pragma unroll
      for (int j = 0; j < 4; ++j)
        acc[i][j] =
            __builtin_amdgcn_mfma_f32_16x16x32_bf16(a[i], bv[j], acc[i][j], 0, 0, 0);
  }
  unsigned short* dst = phi_q + (size_t)b * MDIM * DIMC;
#pragma unroll
  for (int i = 0; i < 4; ++i)
#pragma unroll
    for (int j = 0; j < 4; ++j) {
      const int e = e0 + wc * 64 + j * 16 + l15;
#pragma unroll
      for (int r = 0; r < 4; ++r) {
        const int m = m0 + wr * 64 + i * 16 + q * 4 + r;
        float v = acc[i][j][r];
        v = v > 0.f ? v * 0.0625f : 0.f;
        dst[(size_t)m * DIMC + e] = f2bf(v);
      }
    }
}

// ---------------------------------------------------------------------------
// rowsum[b*256+e] = sum_n phi_k[b][e][n]
// ---------------------------------------------------------------------------
__global__ __launch_bounds__(256) void rowsum_kernel(
    const unsigned short* __restrict__ phi_k, float* __restrict__ rowsum) {
  const int row = blockIdx.x;
  const unsigned short* p = phi_k + (size_t)row * NDIM;
  uint4 v = *(const uint4*)(p + threadIdx.x * 8);
  const unsigned short* u = (const unsigned short*)&v;
  float s = 0.f;
#pragma unroll
  for (int i = 0; i < 8; ++i) s += bf2f(u[i]);
  __shared__ float red[256];
  red[threadIdx.x] = s;
  __syncthreads();
  for (int w = 128; w >= 1; w >>= 1) {
    if (threadIdx.x < w) red[threadIdx.x] += red[threadIdx.x + w];
    __syncthreads();
  }
  if (threadIdx.x == 0) rowsum[row] = red[0];
}

// ---------------------------------------------------------------------------
// kv_t[b][d][e] = sum_n value[b][d][n] * phi_k[b][e][n]   bf16 out, e-contig
// 64(d) x 64(e) tile, K=2048, BK=64. Both operands k(=n)-contiguous.
// ---------------------------------------------------------------------------
__global__ __launch_bounds__(256) void kv_kernel(
    const float* __restrict__ value, const unsigned short* __restrict__ phi_k,
    unsigned short* __restrict__ kv_t) {
  __shared__ unsigned short As[64 * 72];  // [d][n], stride 72 bf16 = 144 B
  __shared__ unsigned short Bs[64 * 72];  // [e][n]
  const int b = blockIdx.z;
  const int d0 = blockIdx.x * 64, e0 = blockIdx.y * 64;
  const int t = threadIdx.x;
  const int lane = t & 63, wave = t >> 6;
  const int wr = wave >> 1, wc = wave & 1;
  const int q = lane >> 4, l15 = lane & 15;
  f32x4 acc[2][2];
#pragma unroll
  for (int i = 0; i < 2; ++i)
#pragma unroll
    for (int j = 0; j < 2; ++j) acc[i][j] = (f32x4){0.f, 0.f, 0.f, 0.f};

  const int row = t >> 2, c16 = (t & 3) << 4;
  const float* asrc = value + ((size_t)b * DIMC + d0 + row) * NDIM + c16;
  const unsigned short* bsrc =
      phi_k + ((size_t)b * DIMC + e0 + row) * NDIM + c16;

  for (int n0 = 0; n0 < NDIM; n0 += 64) {
    __syncthreads();
    {
      float4 f0 = *(const float4*)(asrc + n0);
      float4 f1 = *(const float4*)(asrc + n0 + 4);
      float4 f2 = *(const float4*)(asrc + n0 + 8);
      float4 f3 = *(const float4*)(asrc + n0 + 12);
      unsigned short tmp[16] __attribute__((aligned(16)));
      tmp[0] = f2bf(f0.x); tmp[1] = f2bf(f0.y); tmp[2] = f2bf(f0.z); tmp[3] = f2bf(f0.w);
      tmp[4] = f2bf(f1.x); tmp[5] = f2bf(f1.y); tmp[6] = f2bf(f1.z); tmp[7] = f2bf(f1.w);
      tmp[8] = f2bf(f2.x); tmp[9] = f2bf(f2.y); tmp[10] = f2bf(f2.z); tmp[11] = f2bf(f2.w);
      tmp[12] = f2bf(f3.x); tmp[13] = f2bf(f3.y); tmp[14] = f2bf(f3.z); tmp[15] = f2bf(f3.w);
      *(uint4*)&As[row * 72 + c16] = *(const uint4*)&tmp[0];
      *(uint4*)&As[row * 72 + c16 + 8] = *(const uint4*)&tmp[8];
      uint4 b0 = *(const uint4*)(bsrc + n0);
      uint4 b1 = *(const uint4*)(bsrc + n0 + 8);
      *(uint4*)&Bs[row * 72 + c16] = b0;
      *(uint4*)&Bs[row * 72 + c16 + 8] = b1;
    }
    __syncthreads();
#pragma unroll
    for (int kk = 0; kk < 64; kk += 32) {
      bf16x8 a[2], bv[2];
#pragma unroll
      for (int i = 0; i < 2; ++i)
        a[i] = *(const bf16x8*)&As[(wr * 32 + i * 16 + l15) * 72 + kk + q * 8];
#pragma unroll
      for (int j = 0; j < 2; ++j)
        bv[j] = *(const bf16x8*)&Bs[(wc * 32 + j * 16 + l15) * 72 + kk + q * 8];
#pragma unroll
      for (int i = 0; i < 2; ++i)
#pragma unroll
        for (int j = 0; j < 2; ++j)
          acc[i][j] = __builtin_amdgcn_mfma_f32_16x16x32_bf16(a[i], bv[j],
                                                              acc[i][j], 0, 0, 0);
    }
  }
  unsigned short* dst = kv_t + (size_t)b * DIMC * DIMC;
#pragma unroll
  for (int i = 0; i < 2; ++i)
#pragma unroll
    for (int j = 0; j < 2; ++j) {
      const int e = e0 + wc * 32 + j * 16 + l15;
#pragma unroll
      for (int r = 0; r < 4; ++r) {
        const int d = d0 + wr * 32 + i * 16 + q * 4 + r;
        dst[(size_t)d * DIMC + e] = f2bf(acc[i][j][r]);
      }
    }
}

// ---------------------------------------------------------------------------
// scale[b][m] = 1 / (sum_e phi_q[b][m][e] * rowsum[b][e] + 1e-8)
// one wave per m (4 waves/block)
// ---------------------------------------------------------------------------
__global__ __launch_bounds__(256) void scale_kernel(
    const unsigned short* __restrict__ phi_q, const float* __restrict__ rowsum,
    float* __restrict__ scale) {
  const int gw = blockIdx.x * 4 + (threadIdx.x >> 6);
  const int b = gw >> 11, m = gw & 2047;
  const int lane = threadIdx.x & 63;
  const unsigned short* p = phi_q + ((size_t)b * MDIM + m) * DIMC + lane * 4;
  uint2 v = *(const uint2*)p;
  const unsigned short* u = (const unsigned short*)&v;
  float4 r = *(const float4*)(rowsum + b * DIMC + lane * 4);
  float s = bf2f(u[0]) * r.x + bf2f(u[1]) * r.y + bf2f(u[2]) * r.z +
            bf2f(u[3]) * r.w;
#pragma unroll
  for (int off = 32; off >= 1; off >>= 1) s += __shfl_down(s, off, 64);
  if (lane == 0) scale[(size_t)b * MDIM + m] = 1.f / (s + 1e-8f);
}

// ---------------------------------------------------------------------------
// out[b][d][m] = scale[b][m] * sum_e kv_t[d][e] * phi_q[m][e]   fp32 out
// 128(d) x 128(m) tile, K=256, BK=32. Both operands natural bf16.
// ---------------------------------------------------------------------------
__global__ __launch_bounds__(256) void out_kernel(
    const unsigned short* __restrict__ kv_t,
    const unsigned short* __restrict__ phi_q, const float* __restrict__ scale,
    float* __restrict__ out) {
  __shared__ unsigned short As[128 * 40];  // [d][e]
  __shared__ unsigned short Bs[128 * 40];  // [m][e]
  const int b = blockIdx.z;
  const int m0 = blockIdx.x * 128;
  const int d0 = blockIdx.y * 128;
  const int t = threadIdx.x;
  const int lane = t & 63, wave = t >> 6;
  const int wr = wave >> 1, wc = wave & 1;
  const int q = lane >> 4, l15 = lane & 15;
  f32x4 acc[4][4];
#pragma unroll
  for (int i = 0; i < 4; ++i)
#pragma unroll
    for (int j = 0; j < 4; ++j) acc[i][j] = (f32x4){0.f, 0.f, 0.f, 0.f};

  const int row = t >> 2, c8 = (t & 3) << 3;
  const unsigned short* asrc = kv_t + ((size_t)b * DIMC + d0 + row) * DIMC + c8;
  const unsigned short* bsrc =
      phi_q + ((size_t)b * MDIM + m0 + row) * DIMC + c8;

  for (int k0 = 0; k0 < DIMC; k0 += 32) {
    __syncthreads();
    {
      uint4 a0 = *(const uint4*)(asrc + k0);
      uint4 a1 = *(const uint4*)(asrc + (size_t)64 * DIMC + k0);
      *(uint4*)&As[row * 40 + c8] = a0;
      *(uint4*)&As[(row + 64) * 40 + c8] = a1;
      uint4 b0 = *(const uint4*)(bsrc + k0);
      uint4 b1 = *(const uint4*)(bsrc + (size_t)64 * DIMC + k0);
      *(uint4*)&Bs[row * 40 + c8] = b0;
      *(uint4*)&Bs[(row + 64) * 40 + c8] = b1;
    }
    __syncthreads();
    bf16x8 a[4], bv[4];
#pragma unroll
    for (int i = 0; i < 4; ++i)
      a[i] = *(const bf16x8*)&As[(wr * 64 + i * 16 + l15) * 40 + q * 8];
#pragma unroll
    for (int j = 0; j < 4; ++j)
      bv[j] = *(const bf16x8*)&Bs[(wc * 64 + j * 16 + l15) * 40 + q * 8];
#pragma unroll
    for (int i = 0; i < 4; ++i)
#pragma unroll
      for (int j = 0; j < 4; ++j)
        acc[i][j] =
            __builtin_amdgcn_mfma_f32_16x16x32_bf16(a[i], bv[j], acc[i][j], 0, 0, 0);
  }
  float* ob = out + (size_t)b * DIMC * MDIM;
  const float* scb = scale + (size_t)b * MDIM;
#pragma unroll
  for (int j = 0; j < 4; ++j) {
    const int m = m0 + wc * 64 + j * 16 + l15;
    const float sc = scb[m];
#pragma unroll
    for (int i = 0; i < 4; ++i) {
#pragma unroll
      for (int r = 0; r < 4; ++r) {
        const int d = d0 + wr * 64 + i * 16 + q * 4 + r;
        ob[(size_t)d * MDIM + m] = acc[i][j][r] * sc;
      }
    }
  }
}

extern "C" void kernel_launch(void* const* d_in, const int* in_sizes, int n_in,
                              void* d_out, int out_size, void* d_ws, size_t ws_size,
                              hipStream_t stream) {
  const float* query = (const float*)d_in[0];  // [B,256,M]
  const float* key   = (const float*)d_in[1];  // [B,256,N]
  const float* value = (const float*)d_in[2];  // [B,256,N]
  const float* W     = (const float*)d_in[3];  // [256,256]
  float* out = (float*)d_out;                  // [B,256,M]

  unsigned short* Wt    = (unsigned short*)d_ws;            // 256*256
  unsigned short* phi_q = Wt + 65536;                       // B*M*256 (m-major)
  unsigned short* phi_k = phi_q + (size_t)BSZ * MDIM * DIMC;// B*256*N (e-major)
  unsigned short* kv_t  = phi_k + (size_t)BSZ * DIMC * NDIM;// B*256*256 (d-major)
  float* rowsum = (float*)(kv_t + (size_t)BSZ * DIMC * DIMC);
  float* scale  = rowsum + BSZ * DIMC;

  hipLaunchKernelGGL(wt_kernel, dim3(256), dim3(256), 0, stream, W, Wt);
  hipLaunchKernelGGL(phiq_kernel, dim3(MDIM / 128, DIMC / 128, BSZ), dim3(256),
                     0, stream, query, Wt, phi_q);
  hipLaunchKernelGGL(phik_kernel, dim3(NDIM / 128, DIMC / 128, BSZ), dim3(256),
                     0, stream, key, Wt, phi_k);
  hipLaunchKernelGGL(rowsum_kernel, dim3(BSZ * DIMC), dim3(256), 0, stream,
                     phi_k, rowsum);
  hipLaunchKernelGGL(kv_kernel, dim3(DIMC / 64, DIMC / 64, BSZ), dim3(256), 0,
                     stream, value, phi_k, kv_t);
  hipLaunchKernelGGL(scale_kernel, dim3(BSZ * MDIM / 4), dim3(256), 0, stream,
                     phi_q, rowsum, scale);
  hipLaunchKernelGGL(out_kernel, dim3(MDIM / 128, DIMC / 128, BSZ), dim3(256),
                     0, stream, kv_t, phi_q, scale, out);
}